// Round 3
// baseline (158.353 us; speedup 1.0000x reference)
//
#include <hip/hip_runtime.h>

#define NB 4
#define SEQ 16384
#define D 64
#define NH 8
#define INNER 512

typedef float f4 __attribute__((ext_vector_type(4)));

// ws layout (float offsets)
#define OFF_PART 0                         // [256][4096] block partials of K^T V
#define OFF_S    (256 * 4096)              // [NB][64][64]
#define OFF_P    (OFF_S + NB * 4096)       // Prow [64][512]
#define OFF_Q    (OFF_P + 64 * INNER)      // Qt   [512][64]
#define OFF_XT   (OFF_Q + INNER * D)       // [NB][64][512]  (X^T: [e][64h+d])
#define OFF_G    (OFF_XT + NB * 64 * INNER) // [NB][64][64]

// ---------------------------------------------------------------------------
// kA: blocks 0..255: per-block partial S = K^T V over 256 rows (no LDS,
//     operands direct-from-global; same-address lanes coalesce via L1).
//     blocks 256..263: P_h = Wq_h^T Wk_h  -> Prow[:, 64h..]
//     blocks 264..271: Q_h = Wout_h Wk_h  -> Qt[64h.., :]
// Each wave owns a 32x32 quadrant; lane owns a 4x4 tile. No cross-wave reduce.
// ---------------------------------------------------------------------------
__global__ __launch_bounds__(256) void kA(const float* __restrict__ keys,
                                          const float* __restrict__ values,
                                          const float* __restrict__ Wq,
                                          const float* __restrict__ Wk,
                                          const float* __restrict__ Wout,
                                          float* __restrict__ ws) {
    const int bid = blockIdx.x;
    const int t = threadIdx.x;
    const int w = t >> 6, l = t & 63;
    const int dg = l >> 3, eg = l & 7;
    const int dbase = (w & 1) * 32 + dg * 4;   // output-row base
    const int ebase = (w >> 1) * 32 + eg * 4;  // output-col base

    f4 acc[4];
    #pragma unroll
    for (int a = 0; a < 4; ++a) acc[a] = (f4)0.f;

    if (bid < 256) {
        const int b = bid >> 6;
        const int row0 = (bid & 63) * 256;
        const float* kp = keys   + ((size_t)b * SEQ + row0) * D;
        const float* vp = values + ((size_t)b * SEQ + row0) * D;
        #pragma unroll 4
        for (int n = 0; n < 256; ++n) {
            f4 kv = *(const f4*)(kp + n * D + dbase);
            f4 vv = *(const f4*)(vp + n * D + ebase);
            #pragma unroll
            for (int a = 0; a < 4; ++a)
                acc[a] += kv[a] * vv;          // S[d][e] += k[d]*v[e]
        }
        float* pp = ws + OFF_PART + (size_t)bid * 4096;
        #pragma unroll
        for (int a = 0; a < 4; ++a)
            *(f4*)(pp + (dbase + a) * D + ebase) = acc[a];
    } else if (bid < 264) {
        // P_h[d][j] = sum_i Wq[64h+i][d] * Wk[64h+i][j]   (rank-1 over i)
        const int h = bid - 256;
        const float* wqp = Wq + (size_t)h * 64 * D;
        const float* wkp = Wk + (size_t)h * 64 * D;
        #pragma unroll 4
        for (int i = 0; i < 64; ++i) {
            f4 a4 = *(const f4*)(wqp + i * D + dbase);
            f4 b4 = *(const f4*)(wkp + i * D + ebase);
            #pragma unroll
            for (int a = 0; a < 4; ++a)
                acc[a] += a4[a] * b4;
        }
        float* pp = ws + OFF_P;
        #pragma unroll
        for (int a = 0; a < 4; ++a)
            *(f4*)(pp + (dbase + a) * INNER + h * 64 + ebase) = acc[a];
    } else {
        // Q_h[e][j] = sum_i Wout[e][64h+i] * Wk[64h+i][j]  (dot over i)
        const int h = bid - 264;
        const float* wkp = Wk + (size_t)h * 64 * D;
        #pragma unroll 2
        for (int iq = 0; iq < 16; ++iq) {
            f4 wo[4], wk4[4];
            #pragma unroll
            for (int a = 0; a < 4; ++a)
                wo[a] = *(const f4*)(Wout + (size_t)(dbase + a) * INNER + h * 64 + iq * 4);
            #pragma unroll
            for (int ii = 0; ii < 4; ++ii)
                wk4[ii] = *(const f4*)(wkp + (iq * 4 + ii) * D + ebase);
            #pragma unroll
            for (int a = 0; a < 4; ++a)
                #pragma unroll
                for (int ii = 0; ii < 4; ++ii)
                    acc[a] += wo[a][ii] * wk4[ii];
        }
        float* qp = ws + OFF_Q;
        #pragma unroll
        for (int a = 0; a < 4; ++a)
            *(f4*)(qp + (h * 64 + dbase + a) * D + ebase) = acc[a];
    }
}

// ---------------------------------------------------------------------------
// kB: deterministic reduce of 64 block-partials -> S[b]. 128 blocks.
// ---------------------------------------------------------------------------
__global__ __launch_bounds__(256) void kB(float* __restrict__ ws) {
    const int b = blockIdx.x >> 5;
    const int seg = blockIdx.x & 31;
    const int t = threadIdx.x;
    const int el = seg * 128 + (t & 127);
    const int half = t >> 7;
    const float* pp = ws + OFF_PART + (size_t)b * 64 * 4096 + el;
    float s = 0.f;
    #pragma unroll 8
    for (int p = 0; p < 32; ++p)
        s += pp[(size_t)(half * 32 + p) * 4096];
    __shared__ float red[256];
    red[t] = s;
    __syncthreads();
    if (t < 128)
        ws[OFF_S + b * 4096 + el] = red[t] + red[t + 128];
}

// ---------------------------------------------------------------------------
// kC: X_h = S[b] @ Q_h^T, stored transposed: XT[b][e][64h+d].  32 blocks (b,h).
//     h==0 blocks also zero G[b] (consumed by kD's atomics).
// ---------------------------------------------------------------------------
__global__ __launch_bounds__(256) void kC(float* __restrict__ ws) {
    const int b = blockIdx.x >> 3, h = blockIdx.x & 7;
    const int t = threadIdx.x;
    if (h == 0) {
        f4 z = (f4)0.f;
        #pragma unroll
        for (int m = 0; m < 4; ++m)
            *(f4*)(ws + OFF_G + b * 4096 + t * 16 + m * 4) = z;
    }
    const int w = t >> 6, l = t & 63;
    const int dbase = (w & 1) * 32 + (l >> 3) * 4;
    const int ebase = (w >> 1) * 32 + (l & 7) * 4;
    const float* Sp = ws + OFF_S + b * 4096;
    const float* Qp = ws + OFF_Q + h * 64 * D;
    float acc[4][4];
    #pragma unroll
    for (int a = 0; a < 4; ++a)
        #pragma unroll
        for (int c = 0; c < 4; ++c) acc[a][c] = 0.f;
    #pragma unroll 2
    for (int iq = 0; iq < 16; ++iq) {
        f4 s4[4], q4[4];
        #pragma unroll
        for (int a = 0; a < 4; ++a) s4[a] = *(const f4*)(Sp + (dbase + a) * D + iq * 4);
        #pragma unroll
        for (int c = 0; c < 4; ++c) q4[c] = *(const f4*)(Qp + (ebase + c) * D + iq * 4);
        #pragma unroll
        for (int a = 0; a < 4; ++a)
            #pragma unroll
            for (int c = 0; c < 4; ++c)
                #pragma unroll
                for (int ii = 0; ii < 4; ++ii)
                    acc[a][c] = fmaf(s4[a][ii], q4[c][ii], acc[a][c]);
    }
    float* xp = ws + OFF_XT + (size_t)b * 64 * INNER;
    #pragma unroll
    for (int c = 0; c < 4; ++c) {
        f4 o;
        o[0] = acc[0][c]; o[1] = acc[1][c]; o[2] = acc[2][c]; o[3] = acc[3][c];
        *(f4*)(xp + (size_t)(ebase + c) * INNER + h * 64 + dbase) = o;
    }
}

// ---------------------------------------------------------------------------
// kD: G[b] += (1/N) * Prow[:, kc..kc+32] @ XT[b][:, kc..kc+32]^T.  64 blocks.
// ---------------------------------------------------------------------------
__global__ __launch_bounds__(256) void kD(float* __restrict__ ws) {
    const int b = blockIdx.x >> 4;
    const int kc = (blockIdx.x & 15) * 32;
    const int t = threadIdx.x;
    const int w = t >> 6, l = t & 63;
    const int dbase = (w & 1) * 32 + (l >> 3) * 4;
    const int ebase = (w >> 1) * 32 + (l & 7) * 4;
    const float* Pp = ws + OFF_P;
    const float* Xp = ws + OFF_XT + (size_t)b * 64 * INNER;
    float acc[4][4];
    #pragma unroll
    for (int a = 0; a < 4; ++a)
        #pragma unroll
        for (int c = 0; c < 4; ++c) acc[a][c] = 0.f;
    #pragma unroll
    for (int kq = 0; kq < 8; ++kq) {
        f4 p4[4], x4[4];
        #pragma unroll
        for (int a = 0; a < 4; ++a) p4[a] = *(const f4*)(Pp + (size_t)(dbase + a) * INNER + kc + kq * 4);
        #pragma unroll
        for (int c = 0; c < 4; ++c) x4[c] = *(const f4*)(Xp + (size_t)(ebase + c) * INNER + kc + kq * 4);
        #pragma unroll
        for (int a = 0; a < 4; ++a)
            #pragma unroll
            for (int c = 0; c < 4; ++c)
                #pragma unroll
                for (int ii = 0; ii < 4; ++ii)
                    acc[a][c] = fmaf(p4[a][ii], x4[c][ii], acc[a][c]);
    }
    const float invn = 1.0f / (float)SEQ;
    float* Gp = ws + OFF_G + b * 4096;
    #pragma unroll
    for (int a = 0; a < 4; ++a)
        #pragma unroll
        for (int c = 0; c < 4; ++c)
            atomicAdd(&Gp[(dbase + a) * D + ebase + c], acc[a][c] * invn);
}

// ---------------------------------------------------------------------------
// kE: out[n][e] = q[n][:] . G[:][e] + bout[e].  256 blocks x 256 thr.
// G transposed once per block into XOR-swizzled LDS (bank-conflict-free
// contiguous-slice reads); q direct-from-global (L1-resident 32-row subtiles).
// Wave-tile 64 rows; lane = 4 rows x 8 cols per 32-row subtile.
// ---------------------------------------------------------------------------
__global__ __launch_bounds__(256) void kE(const float* __restrict__ queries,
                                          const float* __restrict__ bout,
                                          const float* __restrict__ ws,
                                          float* __restrict__ out) {
    __shared__ float GTs[4096];
    const int bid = blockIdx.x;
    const int b = bid >> 6;
    const int row0 = (bid & 63) * 256;
    const int t = threadIdx.x;
    {   // stage G^T with quad-XOR swizzle: GT[e][d] at e*64 + ((d>>2)^(e>>3))*4 + (d&3)
        const int d = t >> 2;
        const int e0 = (t & 3) * 16;
        #pragma unroll
        for (int m4 = 0; m4 < 4; ++m4) {
            f4 g = *(const f4*)(ws + OFF_G + b * 4096 + d * 64 + e0 + m4 * 4);
            #pragma unroll
            for (int mm = 0; mm < 4; ++mm) {
                const int e = e0 + m4 * 4 + mm;
                GTs[e * 64 + (((d >> 2) ^ ((e >> 3) & 7)) << 2) + (d & 3)] = g[mm];
            }
        }
    }
    __syncthreads();

    const int w = t >> 6, l = t & 63;
    const int ng = l >> 3, eg = l & 7;
    const f4 bo0 = *(const f4*)(bout + eg * 8);
    const f4 bo1 = *(const f4*)(bout + eg * 8 + 4);
    const float* qp = queries + ((size_t)b * SEQ + row0 + w * 64) * D;
    float* op = out + ((size_t)b * SEQ + row0 + w * 64) * D;

    #pragma unroll
    for (int sub = 0; sub < 2; ++sub) {
        const float* qs = qp + (sub * 32 + ng * 4) * D;
        f4 acc[4][2];
        #pragma unroll
        for (int r = 0; r < 4; ++r) { acc[r][0] = (f4)0.f; acc[r][1] = (f4)0.f; }
        #pragma unroll 4
        for (int dq = 0; dq < 16; ++dq) {
            f4 q4[4], g4[8];
            #pragma unroll
            for (int r = 0; r < 4; ++r)
                q4[r] = *(const f4*)(qs + r * D + dq * 4);
            #pragma unroll
            for (int c = 0; c < 8; ++c) {
                const int e = eg * 8 + c;
                g4[c] = *(const f4*)&GTs[e * 64 + ((dq ^ eg) << 2)];
            }
            #pragma unroll
            for (int r = 0; r < 4; ++r)
                #pragma unroll
                for (int c = 0; c < 8; ++c)
                    #pragma unroll
                    for (int ii = 0; ii < 4; ++ii)
                        acc[r][c >> 2][c & 3] = fmaf(q4[r][ii], g4[c][ii], acc[r][c >> 2][c & 3]);
        }
        #pragma unroll
        for (int r = 0; r < 4; ++r) {
            const int row = (sub * 32 + ng * 4 + r) * D;
            f4 o0 = acc[r][0] + bo0;
            f4 o1 = acc[r][1] + bo1;
            *(f4*)(op + row + eg * 8) = o0;
            *(f4*)(op + row + eg * 8 + 4) = o1;
        }
    }
}

extern "C" void kernel_launch(void* const* d_in, const int* in_sizes, int n_in,
                              void* d_out, int out_size, void* d_ws, size_t ws_size,
                              hipStream_t stream) {
    const float* queries = (const float*)d_in[0];
    const float* keys    = (const float*)d_in[1];
    const float* values  = (const float*)d_in[2];
    const float* Wq      = (const float*)d_in[3];
    const float* Wk      = (const float*)d_in[4];
    const float* Wout    = (const float*)d_in[5];
    const float* bout    = (const float*)d_in[6];
    float* ws = (float*)d_ws;

    kA<<<272, 256, 0, stream>>>(keys, values, Wq, Wk, Wout, ws);
    kB<<<128, 256, 0, stream>>>(ws);
    kC<<<32,  256, 0, stream>>>(ws);
    kD<<<64,  256, 0, stream>>>(ws);
    kE<<<256, 256, 0, stream>>>(queries, bout, ws, (float*)d_out);
}